// Round 13
// baseline (293.077 us; speedup 1.0000x reference)
//
#include <hip/hip_runtime.h>
#include <hip/hip_fp16.h>
#include <stdint.h>

#define HIDDEN 4096
#define FFN    14336
#define MDIM   512
#define G1     224   // FFN / 64
#define G2     64    // HIDDEN / 64
#define BK     64
#define KB_H   128   // HIDDEN/32
#define KB_F   448   // FFN/32

typedef _Float16 f16x8 __attribute__((ext_vector_type(8)));
typedef float f32x4 __attribute__((ext_vector_type(4)));

#define SCHED0() __builtin_amdgcn_sched_barrier(0);
#define LGKM_BAR()                                            \
    asm volatile("s_waitcnt lgkmcnt(0)" ::: "memory");        \
    __builtin_amdgcn_s_barrier();                             \
    __builtin_amdgcn_sched_barrier(0);

// ---------------- fused prep kernel ----------------
// segments: [0,1024) cvt_xp | [1024,2816) sz1 | [2816,4608) sz3 |
//           [4608,6400) sz2 | [6400,8448) zero d_out
__global__ void prep_fused(const float* __restrict__ x,
                           const float* __restrict__ s1, const float* __restrict__ z1,
                           const float* __restrict__ s3, const float* __restrict__ z3,
                           const float* __restrict__ s2, const float* __restrict__ z2,
                           ushort* __restrict__ xbp, uint32_t* __restrict__ szp1,
                           uint32_t* __restrict__ szp3, uint32_t* __restrict__ szp2,
                           float* __restrict__ out) {
    const int b = blockIdx.x, t = threadIdx.x;
    if (b < 1024) {
        // x (f32, row-major) -> xbp (f16, MFMA-fragment-major)
        int i = b * 256 + t;                 // [0, MDIM*HIDDEN/8)
        int ls = i & 63;
        int kb = (i >> 6) & (KB_H - 1);
        int mb = i >> 13;
        int row = mb * 16 + (ls & 15);
        int col = kb * 32 + (ls >> 4) * 8;
        const float4* src = (const float4*)&x[(size_t)row * HIDDEN + col];
        float4 v0 = src[0], v1 = src[1];
        __half2 h0 = __floats2half2_rn(v0.x, v0.y);
        __half2 h1 = __floats2half2_rn(v0.z, v0.w);
        __half2 h2 = __floats2half2_rn(v1.x, v1.y);
        __half2 h3 = __floats2half2_rn(v1.z, v1.w);
        ((uint4*)xbp)[i] = make_uint4(
            __builtin_bit_cast(uint32_t, h0), __builtin_bit_cast(uint32_t, h1),
            __builtin_bit_cast(uint32_t, h2), __builtin_bit_cast(uint32_t, h3));
    } else if (b < 6400) {
        // packed sz: out[2i] = {f16(s0), f16(s1)}, out[2i+1] = {f16(-z0*s0), f16(-z1*s1)}
        const int seg = (b - 1024) / 1792;   // 0:sz1 1:sz3 2:sz2
        const int i = (b - 1024 - seg * 1792) * 256 + t;
        const float* sp = (seg == 0) ? s1 : (seg == 1) ? s3 : s2;
        const float* zp = (seg == 0) ? z1 : (seg == 1) ? z3 : z2;
        uint32_t* op = (seg == 0) ? szp1 : (seg == 1) ? szp3 : szp2;
        float sv0 = sp[2 * i], sv1 = sp[2 * i + 1];
        float zv0 = zp[2 * i], zv1 = zp[2 * i + 1];
        __half2 hs = __floats2half2_rn(sv0, sv1);
        __half2 hn = __floats2half2_rn(-zv0 * sv0, -zv1 * sv1);
        ((uint2*)op)[i] = make_uint2(__builtin_bit_cast(uint32_t, hs),
                                     __builtin_bit_cast(uint32_t, hn));
    } else {
        // zero d_out (split-K atomic accumulation target)
        int i = (b - 6400) * 256 + t;        // one float4 per thread
        ((float4*)out)[i] = make_float4(0.f, 0.f, 0.f, 0.f);
    }
}

// dequant 2 codes -> packed f16 pair: table-select via v_perm + v_pk_fma_f16
__device__ __forceinline__ uint32_t deq2(uint32_t w0, uint32_t w1, uint32_t sh,
                                         uint32_t spair, uint32_t npair) {
    uint32_t c0 = (w0 >> sh) & 3u;
    uint32_t c1 = (w1 >> sh) & 3u;
    uint32_t sel = 0x01000100u + c0 * 0x0202u + c1 * 0x02020000u;
    uint32_t codes = __builtin_amdgcn_perm(0x42004000u, 0x3C000000u, sel); // f16{0,1,2,3}
    __half2 r = __hfma2(__builtin_bit_cast(__half2, codes),
                        __builtin_bit_cast(__half2, spair),
                        __builtin_bit_cast(__half2, npair));
    return __builtin_bit_cast(uint32_t, r);
}

// ---------------- GEMM A: gate/up fused + SwiGLU -> hp (f16 frag-major) ----------------
// R9 structure (best known): BM=256, BN=32, BK=64, 4 waves M-stacked (wave 64x32).
// A: direct frag-major global->reg, prefetched 1 step. B: reg 2-deep -> dequant -> dbuf LDS.

__global__ __launch_bounds__(256, 2)
void gemm_gateup(const ushort* __restrict__ xbp, const uint32_t* __restrict__ qw1,
                 const uint32_t* __restrict__ sz1, const uint32_t* __restrict__ qw3,
                 const uint32_t* __restrict__ sz3, ushort* __restrict__ hp) {
    __shared__ ushort sB1[2][32 * 64];    // 8 KB
    __shared__ ushort sB2[2][32 * 64];    // 8 KB
    __shared__ ushort sE[256 * 32];       // 16 KB epilogue staging

    const int tid = threadIdx.x;
    // XCD swizzle: 896 = 8 x 112; mt fast
    const int idx = ((blockIdx.x & 7) * 112) + (blockIdx.x >> 3);
    const int mt = idx & 1, nt = idx >> 1;
    const int m0 = mt * 256, n0 = nt * 32;

    const int lane = tid & 63, w = tid >> 6;
    const int wm = w * 64;
    const int frow = lane & 15, fk = (lane >> 4) * 8;
    const int sw = (frow & 7) << 3;       // B read-side XOR swizzle

    uint32_t abase[4];
#pragma unroll
    for (int mi = 0; mi < 4; ++mi)
        abase[mi] = (uint32_t)(((m0 >> 4) + w * 4 + mi) * KB_H) * 512 + lane * 8;

    // B staging: threads 0-127 gate, 128-255 up; 2 rows x 8 k each
    const int bi = tid & 127;
    const int rp = bi >> 3;
    const int kc = (bi & 7) * 8;
    const int row0 = rp * 2;
    const int g0 = (n0 + row0) % G1;      // even, <=222; g0+1 no wrap
    const uint32_t* qp = (tid < 128 ? qw1 : qw3) + (size_t)(n0 / 4 + (rp >> 1)) * HIDDEN + kc;
    const uint32_t* zp = (tid < 128 ? sz1 : sz3) + (size_t)g0 * HIDDEN + kc;
    ushort (*sB)[32 * 64] = (tid < 128) ? sB1 : sB2;
    const uint32_t sh0 = 6u - 4u * (uint32_t)(rp & 1);

    f32x4 accG[4][2], accU[4][2];
#pragma unroll
    for (int i = 0; i < 4; ++i)
#pragma unroll
        for (int j = 0; j < 2; ++j) {
            accG[i][j] = (f32x4){0.f, 0.f, 0.f, 0.f};
            accU[i][j] = (f32x4){0.f, 0.f, 0.f, 0.f};
        }

    f16x8 afA[8], afB[8];                 // A-frag sets (static idx mi*2+kk)
    uint4 pwA0, pwA1, pzA0, pzA1, pzA2, pzA3;
    uint4 pwB0, pwB1, pzB0, pzB1, pzB2, pzB3;

#define GU_LDA(AF, tt)                                                         \
    { _Pragma("unroll")                                                        \
      for (int mi = 0; mi < 4; ++mi)                                           \
          _Pragma("unroll")                                                    \
          for (int kk = 0; kk < 2; ++kk)                                       \
              AF[mi * 2 + kk] =                                                \
                  *(const f16x8*)&xbp[abase[mi] + (uint32_t)((tt) * 2 + kk) * 512]; }

#define GU_LD(PW0, PW1, PZ0, PZ1, PZ2, PZ3, k0q)                               \
    PW0 = *(const uint4*)(qp + (k0q));                                         \
    PW1 = *(const uint4*)(qp + (k0q) + 4);                                     \
    PZ0 = *(const uint4*)(zp + (k0q));                                         \
    PZ1 = *(const uint4*)(zp + (k0q) + 4);                                     \
    PZ2 = *(const uint4*)(zp + HIDDEN + (k0q));                                \
    PZ3 = *(const uint4*)(zp + HIDDEN + (k0q) + 4);

#define GU_DEQ(wbuf, PW0, PW1, PZ0, PZ1, PZ2, PZ3)                             \
    { const uint32_t wv[8] = {(PW0).x, (PW0).y, (PW0).z, (PW0).w,              \
                              (PW1).x, (PW1).y, (PW1).z, (PW1).w};             \
      {   const uint32_t sp[4] = {(PZ0).x, (PZ0).z, (PZ1).x, (PZ1).z};         \
          const uint32_t np[4] = {(PZ0).y, (PZ0).w, (PZ1).y, (PZ1).w};         \
          uint32_t o[4];                                                       \
          _Pragma("unroll")                                                    \
          for (int j = 0; j < 4; ++j)                                          \
              o[j] = deq2(wv[2*j], wv[2*j+1], sh0, sp[j], np[j]);              \
          *(uint4*)&sB[wbuf][row0 * 64 + (kc ^ ((row0 & 7) << 3))] =           \
              make_uint4(o[0], o[1], o[2], o[3]);                              \
      }                                                                        \
      {   const uint32_t sp[4] = {(PZ2).x, (PZ2).z, (PZ3).x, (PZ3).z};         \
          const uint32_t np[4] = {(PZ2).y, (PZ2).w, (PZ3).y, (PZ3).w};         \
          uint32_t o[4];                                                       \
          _Pragma("unroll")                                                    \
          for (int j = 0; j < 4; ++j)                                          \
              o[j] = deq2(wv[2*j], wv[2*j+1], sh0 - 2u, sp[j], np[j]);         \
          const int row1 = row0 + 1;                                           \
          *(uint4*)&sB[wbuf][row1 * 64 + (kc ^ ((row1 & 7) << 3))] =           \
              make_uint4(o[0], o[1], o[2], o[3]);                              \
      } }

#define GU_COMP(AF, rbuf)                                                      \
    { _Pragma("unroll")                                                        \
      for (int kk = 0; kk < 2; ++kk) {                                         \
          const int col = ((kk * 32) + fk) ^ sw;                               \
          f16x8 bg0 = *(const f16x8*)&sB1[rbuf][frow * 64 + col];              \
          f16x8 bg1 = *(const f16x8*)&sB1[rbuf][(16 + frow) * 64 + col];       \
          f16x8 bu0 = *(const f16x8*)&sB2[rbuf][frow * 64 + col];              \
          f16x8 bu1 = *(const f16x8*)&sB2[rbuf][(16 + frow) * 64 + col];       \
          _Pragma("unroll")                                                    \
          for (int mi = 0; mi < 4; ++mi) {                                     \
              accG[mi][0] = __builtin_amdgcn_mfma_f32_16x16x32_f16(AF[mi*2+kk], bg0, accG[mi][0], 0, 0, 0); \
              accG[mi][1] = __builtin_amdgcn_mfma_f32_16x16x32_f16(AF[mi*2+kk], bg1, accG[mi][1], 0, 0, 0); \
              accU[mi][0] = __builtin_amdgcn_mfma_f32_16x16x32_f16(AF[mi*2+kk], bu0, accU[mi][0], 0, 0, 0); \
              accU[mi][1] = __builtin_amdgcn_mfma_f32_16x16x32_f16(AF[mi*2+kk], bu1, accU[mi][1], 0, 0, 0); \
          } } }

#define GU_STEP(tcur, AFW, AFR, WBUF, RBUF, PW0, PW1, PZ0, PZ1, PZ2, PZ3, DOLDA, DOLQ) \
    { if (DOLDA) { GU_LDA(AFW, (tcur) + 1) } SCHED0()                          \
      GU_DEQ(WBUF, PW0, PW1, PZ0, PZ1, PZ2, PZ3)                               \
      if (DOLQ) { GU_LD(PW0, PW1, PZ0, PZ1, PZ2, PZ3, ((tcur) + 3) * BK) }     \
      GU_COMP(AFR, RBUF)                                                       \
      LGKM_BAR() }

    // prologue: tile0 regs + A-frags; DEQ tile0 -> buf0; tile1/2 qw-sets in flight
    GU_LD(pwA0, pwA1, pzA0, pzA1, pzA2, pzA3, 0)
    GU_LDA(afA, 0)
    GU_DEQ(0, pwA0, pwA1, pzA0, pzA1, pzA2, pzA3)
    GU_LD(pwA0, pwA1, pzA0, pzA1, pzA2, pzA3, BK)
    GU_LD(pwB0, pwB1, pzB0, pzB1, pzB2, pzB3, 2 * BK)
    LGKM_BAR()

    for (int t = 0; t < 60; t += 2) {
        GU_STEP(t,     afB, afA, 1, 0, pwA0, pwA1, pzA0, pzA1, pzA2, pzA3, 1, 1)
        GU_STEP(t + 1, afA, afB, 0, 1, pwB0, pwB1, pzB0, pzB1, pzB2, pzB3, 1, 1)
    }
    GU_STEP(60, afB, afA, 1, 0, pwA0, pwA1, pzA0, pzA1, pzA2, pzA3, 1, 1)
    GU_STEP(61, afA, afB, 0, 1, pwB0, pwB1, pzB0, pzB1, pzB2, pzB3, 1, 0)
    GU_STEP(62, afB, afA, 1, 0, pwA0, pwA1, pzA0, pzA1, pzA2, pzA3, 1, 0)
    GU_COMP(afB, 1)   // tile 63

    // ---- epilogue: silu(gate)*up -> sE -> frag-major stores to hp ----
    const int rb = (lane >> 4) * 4, cb = lane & 15;
#pragma unroll
    for (int mi = 0; mi < 4; ++mi)
#pragma unroll
        for (int ni = 0; ni < 2; ++ni) {
            f32x4 g = accG[mi][ni], u = accU[mi][ni];
            const int row = wm + mi * 16 + rb;
            const int colx = ni * 16 + cb;
#pragma unroll
            for (int r = 0; r < 4; ++r) {
                float gv = g[r];
                float hv = __fdividef(gv, 1.0f + __expf(-gv)) * u[r];
                __half hh = __float2half(hv);
                sE[(row + r) * 32 + colx] = __builtin_bit_cast(ushort, hh);
            }
        }
    __syncthreads();
    {
#pragma unroll
        for (int j = 0; j < 4; ++j) {
            const int slot = tid + j * 256;          // [0,1024): 16 mb-blocks x 64 lanes
            const int mbi = slot >> 6, ls = slot & 63;
            uint4 v = *(const uint4*)&sE[(mbi * 16 + (ls & 15)) * 32 + (ls >> 4) * 8];
            *(uint4*)&hp[(size_t)(((m0 >> 4) + mbi) * KB_F + nt) * 512 + ls * 8] = v;
        }
    }
#undef GU_LDA
#undef GU_LD
#undef GU_DEQ
#undef GU_COMP
#undef GU_STEP
}

// ---------------- GEMM B: out += hp @ w2^T (split-K = 2, atomic epilogue) ----------------
// R9 structure: BM=256, BN=32, BK=64; A direct frag-major from hp; B dbuf LDS dequant.

__global__ __launch_bounds__(256, 2)
void gemm_down(const ushort* __restrict__ hp, const uint32_t* __restrict__ qw2,
               const uint32_t* __restrict__ sz2, float* __restrict__ out) {
    __shared__ ushort sBd[2][32 * 64];    // 8 KB

    const int tid = threadIdx.x;
    // 512 = 8 x 64 XCD swizzle
    const int idx = ((blockIdx.x & 7) * 64) + (blockIdx.x >> 3);
    const int mt = idx & 1, nt = (idx >> 1) & 127, sk = idx >> 8;
    const int m0 = mt * 256, n0 = nt * 32;
    const int kb0 = sk * 224;             // kbeg/32
    const int kbeg = sk * (FFN / 2);

    const int lane = tid & 63, w = tid >> 6;
    const int wm = w * 64;
    const int frow = lane & 15, fk = (lane >> 4) * 8;
    const int sw = (frow & 7) << 3;

    uint32_t abase[4];
#pragma unroll
    for (int mi = 0; mi < 4; ++mi)
        abase[mi] = (uint32_t)(((m0 >> 4) + w * 4 + mi) * KB_F + kb0) * 512 + lane * 8;

    // B staging: 1 row x 8 k per thread
    const int r = tid >> 3;
    const int kc = (tid & 7) * 8;
    const int g = ((nt & 1) * 32) + r;    // (n0 + r) % 64
    const uint32_t* qp = qw2 + (size_t)(n0 / 4 + (r >> 2)) * FFN + kbeg + kc;
    const uint32_t* zp = sz2 + (size_t)g * FFN + kbeg + kc;
    const uint32_t sh = 6u - 2u * (uint32_t)(r & 3);

    f32x4 acc[4][2];
#pragma unroll
    for (int i = 0; i < 4; ++i)
#pragma unroll
        for (int j = 0; j < 2; ++j) acc[i][j] = (f32x4){0.f, 0.f, 0.f, 0.f};

    f16x8 afA[8], afB[8];
    uint4 pwA0, pwA1, pzA0, pzA1;
    uint4 pwB0, pwB1, pzB0, pzB1;

#define GD_LDA(AF, tt)                                                         \
    { _Pragma("unroll")                                                        \
      for (int mi = 0; mi < 4; ++mi)                                           \
          _Pragma("unroll")                                                    \
          for (int kk = 0; kk < 2; ++kk)                                       \
              AF[mi * 2 + kk] =                                                \
                  *(const f16x8*)&hp[abase[mi] + (uint32_t)((tt) * 2 + kk) * 512]; }

#define GD_LD(PW0, PW1, PZ0, PZ1, k0q)                                         \
    PW0 = *(const uint4*)(qp + (k0q));                                         \
    PW1 = *(const uint4*)(qp + (k0q) + 4);                                     \
    PZ0 = *(const uint4*)(zp + (k0q));                                         \
    PZ1 = *(const uint4*)(zp + (k0q) + 4);

#define GD_DEQ(wbuf, PW0, PW1, PZ0, PZ1)                                       \
    { const uint32_t wv[8] = {(PW0).x, (PW0).y, (PW0).z, (PW0).w,              \
                              (PW1).x, (PW1).y, (PW1).z, (PW1).w};             \
      const uint32_t sp[4] = {(PZ0).x, (PZ0).z, (PZ1).x, (PZ1).z};             \
      const uint32_t np[4] = {(PZ0).y, (PZ0).w, (PZ1).y, (PZ1).w};             \
      uint32_t o[4];                                                           \
      _Pragma("unroll")                                                        \
      for (int j = 0; j < 4; ++j)                                              \
          o[j] = deq2(wv[2*j], wv[2*j+1], sh, sp[j], np[j]);                   \
      *(uint4*)&sBd[wbuf][r * 64 + (kc ^ ((r & 7) << 3))] =                    \
          make_uint4(o[0], o[1], o[2], o[3]); }

#define GD_COMP(AF, rbuf)                                                      \
    { _Pragma("unroll")                                                        \
      for (int kk = 0; kk < 2; ++kk) {                                         \
          const int col = ((kk * 32) + fk) ^ sw;                               \
          f16x8 bf0 = *(const f16x8*)&sBd[rbuf][frow * 64 + col];              \
          f16x8 bf1 = *(const f16x8*)&sBd[rbuf][(16 + frow) * 64 + col];       \
          _Pragma("unroll")                                                    \
          for (int mi = 0; mi < 4; ++mi) {                                     \
              acc[mi][0] = __builtin_amdgcn_mfma_f32_16x16x32_f16(AF[mi*2+kk], bf0, acc[mi][0], 0, 0, 0); \
              acc[mi][1] = __builtin_amdgcn_mfma_f32_16x16x32_f16(AF[mi*2+kk], bf1, acc[mi][1], 0, 0, 0); \
          } } }

#define GD_STEP(tcur, AFW, AFR, WBUF, RBUF, PW0, PW1, PZ0, PZ1, DOLDA, DOLQ)   \
    { if (DOLDA) { GD_LDA(AFW, (tcur) + 1) } SCHED0()                          \
      GD_DEQ(WBUF, PW0, PW1, PZ0, PZ1)                                         \
      if (DOLQ) { GD_LD(PW0, PW1, PZ0, PZ1, ((tcur) + 3) * BK) }               \
      GD_COMP(AFR, RBUF)                                                       \
      LGKM_BAR() }

    GD_LD(pwA0, pwA1, pzA0, pzA1, 0)
    GD_LDA(afA, 0)
    GD_DEQ(0, pwA0, pwA1, pzA0, pzA1)
    GD_LD(pwA0, pwA1, pzA0, pzA1, BK)
    GD_LD(pwB0, pwB1, pzB0, pzB1, 2 * BK)
    LGKM_BAR()

    for (int t = 0; t < 108; t += 2) {
        GD_STEP(t,     afB, afA, 1, 0, pwA0, pwA1, pzA0, pzA1, 1, 1)
        GD_STEP(t + 1, afA, afB, 0, 1, pwB0, pwB1, pzB0, pzB1, 1, 1)
    }
    GD_STEP(108, afB, afA, 1, 0, pwA0, pwA1, pzA0, pzA1, 1, 1)
    GD_STEP(109, afA, afB, 0, 1, pwB0, pwB1, pzB0, pzB1, 1, 0)
    GD_STEP(110, afB, afA, 1, 0, pwA0, pwA1, pzA0, pzA1, 1, 0)
    GD_COMP(afB, 1)   // tile 111

    // ---- epilogue: atomic split-K accumulation into zeroed d_out ----
    const int rb = (lane >> 4) * 4, cb = lane & 15;
#pragma unroll
    for (int mi = 0; mi < 4; ++mi)
#pragma unroll
        for (int ni = 0; ni < 2; ++ni) {
            f32x4 a = acc[mi][ni];
            const int mm = m0 + wm + mi * 16 + rb;
            const int nn = n0 + ni * 16 + cb;
#pragma unroll
            for (int rr = 0; rr < 4; ++rr)
                atomicAdd(&out[(size_t)(mm + rr) * HIDDEN + nn], a[rr]);
        }
#undef GD_LDA
#undef GD_LD
#undef GD_DEQ
#undef GD_COMP
#undef GD_STEP
}

// ---------------- launch ----------------

extern "C" void kernel_launch(void* const* d_in, const int* in_sizes, int n_in,
                              void* d_out, int out_size, void* d_ws, size_t ws_size,
                              hipStream_t stream) {
    (void)in_sizes; (void)n_in; (void)out_size; (void)ws_size;

    const float* x  = (const float*)d_in[0];
    const uint32_t* qw1 = (const uint32_t*)d_in[1];
    const float* s1 = (const float*)d_in[2];
    const float* z1 = (const float*)d_in[3];
    const uint32_t* qw3 = (const uint32_t*)d_in[4];
    const float* s3 = (const float*)d_in[5];
    const float* z3 = (const float*)d_in[6];
    const uint32_t* qw2 = (const uint32_t*)d_in[7];
    const float* s2 = (const float*)d_in[8];
    const float* z2 = (const float*)d_in[9];
    float* out = (float*)d_out;

    // ws: xbp 4.19M | sz1 3.67M | sz3 3.67M | sz2 3.67M | hp(f16) 14.68M
    char* ws = (char*)d_ws;
    ushort*   xbp  = (ushort*)ws;
    uint32_t* szp1 = (uint32_t*)(ws + (size_t)MDIM * HIDDEN * 2);
    uint32_t* szp3 = szp1 + (size_t)G1 * HIDDEN;
    uint32_t* szp2 = szp3 + (size_t)G1 * HIDDEN;
    ushort*   hp   = (ushort*)(szp2 + (size_t)G2 * FFN);

    prep_fused<<<8448, 256, 0, stream>>>(x, s1, z1, s3, z3, s2, z2,
                                         xbp, szp1, szp3, szp2, out);
    gemm_gateup<<<(FFN / 32) * (MDIM / 256), 256, 0, stream>>>(xbp, qw1, szp1, qw3, szp3, hp);
    gemm_down<<<2 * (MDIM / 256) * (HIDDEN / 32), 256, 0, stream>>>(hp, qw2, szp2, out);
}